// Round 20
// baseline (137.133 us; speedup 1.0000x reference)
//
#include <hip/hip_runtime.h>
#include <hip/hip_bf16.h>
#include <cstdint>

// HaloAttention: B=4, H=W=128, C=256, 8 heads, kd=32, block=8, halo=2, kvk=12.
// conv_prep -> gemm_qkv6 (BK=32 dbuf prefetch, XCD-swizzled) -> attn (augmented-K,
// log2 softmax, T14 async staging, setprio, 2 barriers) -> mfma_gemm (f32, dbuf, XCD).

#define KVK 12
#define NKEYS 144
#define VT_S 160
#define PT_S 168
#define LOG2E 1.4426950408889634f

typedef unsigned int u32;
typedef unsigned long long u64;
typedef unsigned short u16;
typedef __attribute__((ext_vector_type(8))) __bf16 bf16x8;
typedef __attribute__((ext_vector_type(4))) float f32x4;

__device__ __forceinline__ u16 f2bf(float f) {
    u32 x = __float_as_uint(f);
    return (u16)((x + 0x7fffu + ((x >> 16) & 1u)) >> 16);
}
__device__ __forceinline__ u32 cvtpk(float lo, float hi) {
    u32 d;
    asm("v_cvt_pk_bf16_f32 %0, %1, %2" : "=v"(d) : "v"(lo), "v"(hi));
    return d;
}
__device__ __forceinline__ float max3f(float a, float b, float c) {
    float d;
    asm("v_max3_f32 %0, %1, %2, %3" : "=v"(d) : "v"(a), "v"(b), "v"(c));
    return d;
}
__device__ __forceinline__ float exp2a(float x) {
    float d;
    asm("v_exp_f32 %0, %1" : "=v"(d) : "v"(x));
    return d;
}
__device__ __forceinline__ void gload16(const void* g, void* l) {
    __builtin_amdgcn_global_load_lds(
        (const __attribute__((address_space(1))) void*)g,
        (__attribute__((address_space(3))) void*)l, 16, 0, 0);
}
__device__ __forceinline__ u32 pack2(float lo, float hi) {
    return (u32)f2bf(lo) | ((u32)f2bf(hi) << 16);
}

// ---------------- conv (x->bf16) + weight/emb prep, one dispatch ----------------
__global__ __launch_bounds__(256) void conv_prep(const float* __restrict__ x,
                                                 u16* __restrict__ xb,
                                                 const float* __restrict__ wq,
                                                 const float* __restrict__ wkv,
                                                 const float* __restrict__ wout,
                                                 u16* __restrict__ wT,
                                                 u16* __restrict__ woutT,
                                                 const float* __restrict__ emb_h,
                                                 const float* __restrict__ emb_w,
                                                 u16* __restrict__ embT) {
    int blk = blockIdx.x, t = threadIdx.x;
    if (blk < 8192) {
        int i = blk * 256 + t;
        const float4* p = reinterpret_cast<const float4*>(x) + (long)i * 2;
        float4 a = p[0], b = p[1];
        uint4 o;
        o.x = pack2(a.x, a.y); o.y = pack2(a.z, a.w);
        o.z = pack2(b.x, b.y); o.w = pack2(b.z, b.w);
        reinterpret_cast<uint4*>(xb)[i] = o;
        return;
    }
    blk -= 8192;
    if (blk < 256) {
        int idx = blk * 256 + t; int nn = idx >> 8, k = idx & 255;
        wT[idx] = f2bf(wq[(long)k * 256 + nn]);
    } else if (blk < 768) {
        int idx = (blk - 256) * 256 + t; int nn = idx >> 8, k = idx & 255;
        float v = wkv[(long)k * 512 + nn];
        if ((nn & 32) == 0) v *= 0.2550348642f;  // (1/sqrt(32)) * log2(e)
        wT[65536 + idx] = f2bf(v);
    } else if (blk < 1024) {
        int idx = (blk - 768) * 256 + t; int nn = idx >> 8, k = idx & 255;
        woutT[idx] = f2bf(wout[(long)k * 256 + nn]);
    } else if (blk == 1024) {
        for (int i = t; i < 1024; i += 256) {
            int p = i >> 5, d = i & 31;
            embT[i] = (p < 23) ? f2bf(emb_h[d * 23 + p]) : 0;
        }
    } else {
        for (int i = t; i < 1024; i += 256) {
            int p = i >> 5, d = i & 31;
            embT[1024 + i] = (p < 23) ? f2bf(emb_w[d * 23 + p]) : 0;
        }
    }
}

// -------- QKV GEMM: [Q|KV] = xb @ [wq|wkv]^T, BK=32 dbuf prefetch, XCD grid -----
// Loop: {sync (drains this tile's loads, issued one compute-phase ago);
//        issue next tile's loads into buf^1; compute this tile}. 1 barrier/step.
__global__ __launch_bounds__(256) void gemm_qkv6(const u16* __restrict__ A,
                                                 const u16* __restrict__ WT,
                                                 u16* __restrict__ Qb,
                                                 u16* __restrict__ KVb) {
    __shared__ u16 As[8192];   // 2 buffers x [128 rows][32 k]
    __shared__ u16 Bs[8192];
    const int t = threadIdx.x;
    const int bid = blockIdx.x;
    const int mIdx = (bid / 48) * 8 + (bid & 7);
    const int nt = (bid >> 3) % 6;
    const int w = t >> 6, lane = t & 63;
    const long m0 = (long)mIdx * 128;
    const long n0 = (long)nt * 128;
    const int wr = w >> 1, wc = w & 1;
    const int r = lane & 15, g = lane >> 4;

    f32x4 acc[4][4];
    #pragma unroll
    for (int i = 0; i < 4; ++i)
        #pragma unroll
        for (int j = 0; j < 4; ++j) acc[i][j] = (f32x4){0.f, 0.f, 0.f, 0.f};

    const int u0 = w * 128 + lane;
    const int row0 = u0 >> 2, cs0 = (u0 & 3) * 8;
    const int u1 = u0 + 64;
    const int row1 = u1 >> 2, cs1 = (u1 & 3) * 8;
    const u16* Ag0 = A + (m0 + row0) * 256 + cs0;
    const u16* Ag1 = A + (m0 + row1) * 256 + cs1;
    const u16* Bg0 = WT + (n0 + row0) * 256 + cs0;
    const u16* Bg1 = WT + (n0 + row1) * 256 + cs1;
    const int wb = w * 1024;

    // prologue: stage tile 0 into buffer 0
    gload16(Ag0, &As[wb]);
    gload16(Ag1, &As[wb + 512]);
    gload16(Bg0, &Bs[wb]);
    gload16(Bg1, &Bs[wb + 512]);

    #pragma unroll
    for (int k = 0; k < 8; ++k) {
        __syncthreads();   // vmcnt(0)+barrier: tile k's loads landed, all waves past k-1 compute
        if (k < 7) {
            const int nb = ((k + 1) & 1) * 4096;
            const int ko = (k + 1) * 32;
            gload16(Ag0 + ko, &As[nb + wb]);
            gload16(Ag1 + ko, &As[nb + wb + 512]);
            gload16(Bg0 + ko, &Bs[nb + wb]);
            gload16(Bg1 + ko, &Bs[nb + wb + 512]);
        }
        const int cb = (k & 1) * 4096;
        bf16x8 a[4], b[4];
        #pragma unroll
        for (int i = 0; i < 4; ++i)
            a[i] = *reinterpret_cast<const bf16x8*>(
                &As[cb + (wr * 64 + i * 16 + r) * 32 + g * 8]);
        #pragma unroll
        for (int j = 0; j < 4; ++j)
            b[j] = *reinterpret_cast<const bf16x8*>(
                &Bs[cb + (wc * 64 + j * 16 + r) * 32 + g * 8]);
        #pragma unroll
        for (int i = 0; i < 4; ++i)
            #pragma unroll
            for (int j = 0; j < 4; ++j)
                acc[i][j] = __builtin_amdgcn_mfma_f32_16x16x32_bf16(b[j], a[i], acc[i][j], 0, 0, 0);
    }

    const bool isQ = (nt < 2);
    #pragma unroll
    for (int i = 0; i < 4; ++i) {
        long row = m0 + wr * 64 + i * 16 + r;
        #pragma unroll
        for (int j = 0; j < 4; ++j) {
            long colb = n0 + wc * 64 + j * 16 + g * 4;
            uint2 st;
            st.x = cvtpk(acc[i][j][0], acc[i][j][1]);
            st.y = cvtpk(acc[i][j][2], acc[i][j][3]);
            if (isQ) *reinterpret_cast<uint2*>(Qb + row * 256 + colb) = st;
            else     *reinterpret_cast<uint2*>(KVb + row * 512 + colb - 256) = st;
        }
    }
}

// ------- MFMA GEMM (final): C f32 = A bf16 * BT^T, BK=32 dbuf prefetch, XCD -----
__global__ __launch_bounds__(256) void mfma_gemm(const u16* __restrict__ A,
                                                 const u16* __restrict__ BT,
                                                 float* __restrict__ C, int N) {
    __shared__ u16 As[8192];
    __shared__ u16 Bs[8192];
    const int t = threadIdx.x;
    const int bid = blockIdx.x;
    const int mIdx = (bid / 16) * 8 + (bid & 7);
    const int nt = (bid >> 3) & 1;
    const int w = t >> 6, lane = t & 63;
    const long m0 = (long)mIdx * 128;
    const long n0 = (long)nt * 128;
    const int wr = w >> 1, wc = w & 1;
    const int r = lane & 15, g = lane >> 4;

    f32x4 acc[4][4];
    #pragma unroll
    for (int i = 0; i < 4; ++i)
        #pragma unroll
        for (int j = 0; j < 4; ++j) acc[i][j] = (f32x4){0.f, 0.f, 0.f, 0.f};

    const int u0 = w * 128 + lane;
    const int row0 = u0 >> 2, cs0 = (u0 & 3) * 8;
    const int u1 = u0 + 64;
    const int row1 = u1 >> 2, cs1 = (u1 & 3) * 8;
    const u16* Ag0 = A + (m0 + row0) * 256 + cs0;
    const u16* Ag1 = A + (m0 + row1) * 256 + cs1;
    const u16* Bg0 = BT + (n0 + row0) * 256 + cs0;
    const u16* Bg1 = BT + (n0 + row1) * 256 + cs1;
    const int wb = w * 1024;

    gload16(Ag0, &As[wb]);
    gload16(Ag1, &As[wb + 512]);
    gload16(Bg0, &Bs[wb]);
    gload16(Bg1, &Bs[wb + 512]);

    #pragma unroll
    for (int k = 0; k < 8; ++k) {
        __syncthreads();
        if (k < 7) {
            const int nb = ((k + 1) & 1) * 4096;
            const int ko = (k + 1) * 32;
            gload16(Ag0 + ko, &As[nb + wb]);
            gload16(Ag1 + ko, &As[nb + wb + 512]);
            gload16(Bg0 + ko, &Bs[nb + wb]);
            gload16(Bg1 + ko, &Bs[nb + wb + 512]);
        }
        const int cb = (k & 1) * 4096;
        bf16x8 a[4], b[4];
        #pragma unroll
        for (int i = 0; i < 4; ++i)
            a[i] = *reinterpret_cast<const bf16x8*>(
                &As[cb + (wr * 64 + i * 16 + r) * 32 + g * 8]);
        #pragma unroll
        for (int j = 0; j < 4; ++j)
            b[j] = *reinterpret_cast<const bf16x8*>(
                &Bs[cb + (wc * 64 + j * 16 + r) * 32 + g * 8]);
        #pragma unroll
        for (int i = 0; i < 4; ++i)
            #pragma unroll
            for (int j = 0; j < 4; ++j)
                acc[i][j] = __builtin_amdgcn_mfma_f32_16x16x32_bf16(b[j], a[i], acc[i][j], 0, 0, 0);
    }

    #pragma unroll
    for (int i = 0; i < 4; ++i) {
        long row = m0 + wr * 64 + i * 16 + r;
        #pragma unroll
        for (int j = 0; j < 4; ++j) {
            long colb = n0 + wc * 64 + j * 16 + g * 4;
            float4 st = make_float4(acc[i][j][0], acc[i][j][1], acc[i][j][2], acc[i][j][3]);
            *reinterpret_cast<float4*>(C + row * N + colb) = st;
        }
    }
}

// ---------------- MFMA Attention (frozen from R19) ----------------
#define UNITLOAD(U, VK, VV, KD, VB) {                                          \
    int kk_ = (U) >> 2, p_ = (U) & 3;                                          \
    int ky_ = (kk_ * 171) >> 11, kx_ = kk_ - 12 * ky_;                         \
    int gy_ = by * 8 + ky_ - 2, gx_ = bx * 8 + kx_ - 2;                        \
    if (((unsigned)gy_ < 128u) && ((unsigned)gx_ < 128u)) {                    \
        const u16* bp_ = KVb + (((long)b * 128 + gy_) * 128 + gx_) * 512 + n * 64 + p_ * 8; \
        VK = *reinterpret_cast<const uint4*>(bp_);                             \
        VV = *reinterpret_cast<const uint4*>(bp_ + 32);                        \
    }                                                                          \
    KD = kk_ * 64 + ((p_ * 8) ^ ((kk_ & 7) << 3));                             \
    VB = (p_ * 8) * VT_S + (kk_ ^ (p_ << 3));                                  \
}
#define VSCAT(VV, VB) {                                                        \
    u16 tmp_[8];                                                               \
    *reinterpret_cast<uint4*>(tmp_) = VV;                                      \
    _Pragma("unroll")                                                          \
    for (int i_ = 0; i_ < 8; ++i_) Vt[(VB) + i_ * VT_S] = tmp_[i_];            \
}

__global__ __launch_bounds__(256, 5) void attn_mfma(const u16* __restrict__ Qb,
                                                    const u16* __restrict__ KVb,
                                                    const u16* __restrict__ embT,
                                                    u16* __restrict__ Ob) {
    __shared__ __align__(16) char blob[22528];
    u16* Ks  = (u16*)blob;               // [144][64] swizzled: 0..31 K*s*l2e, 32..55 onehots
    u16* Qe  = (u16*)(blob + 18432);     // [64][32]: rel*log2e dims + zero tail
    u16* PT  = (u16*)blob;               // [64][PT_S] overlay after QK (21504B)
    __shared__ u16 Vt[32 * VT_S];        // V^T [d][k], swizzled, cols 144..159 zero

    const int gblk = blockIdx.x;
    const int n = gblk & 7;
    const int bx = (gblk >> 3) & 15;
    const int by = (gblk >> 7) & 15;
    const int b = gblk >> 11;
    const int t = threadIdx.x;
    const int w = t >> 6, lane = t & 63;
    const int g = lane >> 4, r = lane & 15;

    const int q = w * 16 + r;
    const int qi = q >> 3, qj = q & 7;
    const long qrow = ((long)b * 128 + by * 8 + qi) * 128 + bx * 8 + qj;

    // ---- issue ALL global loads up front ----
    bf16x8 qa1 = *reinterpret_cast<const bf16x8*>(Qb + qrow * 256 + n * 32 + g * 8);
    bf16x8 ah0 = *reinterpret_cast<const bf16x8*>(embT + r * 32 + g * 8);
    bf16x8 ah1 = *reinterpret_cast<const bf16x8*>(embT + (16 + r) * 32 + g * 8);
    bf16x8 aw0 = *reinterpret_cast<const bf16x8*>(embT + 1024 + r * 32 + g * 8);
    bf16x8 aw1 = *reinterpret_cast<const bf16x8*>(embT + 1024 + (16 + r) * 32 + g * 8);

    uint4 z4 = make_uint4(0u, 0u, 0u, 0u);
    uint4 vK0 = z4, vV0 = z4, vK1 = z4, vV1 = z4, vK2 = z4, vV2 = z4;
    int kd0 = 0, vb0 = 0, kd1 = 0, vb1 = 0, kd2 = 0, vb2 = 0;
    UNITLOAD(t, vK0, vV0, kd0, vb0);
    UNITLOAD(t + 256, vK1, vV1, kd1, vb1);
    if (t < 64) UNITLOAD(t + 512, vK2, vV2, kd2, vb2);

    // ---- load-independent work first: one-hot ext cols + pads (covers latency) ----
    for (int u = t; u < 576; u += 256) {
        int kk = u >> 2, uu = u & 3;
        int ky = (kk * 171) >> 11;
        int kx = kk - 12 * ky;
        int hy = ky - 8 * uu;
        int hx = 12 + kx - 8 * uu;
        u64 lo = 0, hi = 0;
        if ((unsigned)hy < 4u) lo |= 0x3F80ULL << (hy * 16);
        else if ((unsigned)hy < 8u) hi |= 0x3F80ULL << ((hy - 4) * 16);
        if ((unsigned)hx < 4u) lo |= 0x3F80ULL << (hx * 16);
        else if ((unsigned)hx < 8u) hi |= 0x3F80ULL << ((hx - 4) * 16);
        int col = (32 + uu * 8) ^ ((kk & 7) << 3);
        u64* dst = reinterpret_cast<u64*>(&Ks[kk * 64 + col]);
        dst[0] = lo;
        dst[1] = hi;
    }
    if (t < 64) *reinterpret_cast<uint4*>(&Qe[t * 32 + 24]) = z4;
    if (t >= 224) {
        int d = t - 224;
        int sw = ((d >> 3) & 3) << 3;
        *reinterpret_cast<uint4*>(&Vt[d * VT_S + (144 ^ sw)]) = z4;
        *reinterpret_cast<uint4*>(&Vt[d * VT_S + (152 ^ sw)]) = z4;
    }

    // ---- K -> LDS (first use of the KV loads) ----
    *reinterpret_cast<uint4*>(&Ks[kd0]) = vK0;
    *reinterpret_cast<uint4*>(&Ks[kd1]) = vK1;
    if (t < 64) *reinterpret_cast<uint4*>(&Ks[kd2]) = vK2;

    // ---- phase 1: rel-MFMA -> Qe (x log2e) ----
    {
        f32x4 z = (f32x4){0.f, 0.f, 0.f, 0.f};
        __builtin_amdgcn_s_setprio(1);
        f32x4 rh0 = __builtin_amdgcn_mfma_f32_16x16x32_bf16(ah0, qa1, z, 0, 0, 0);
        f32x4 rh1 = __builtin_amdgcn_mfma_f32_16x16x32_bf16(ah1, qa1, z, 0, 0, 0);
        f32x4 rw0 = __builtin_amdgcn_mfma_f32_16x16x32_bf16(aw0, qa1, z, 0, 0, 0);
        f32x4 rw1 = __builtin_amdgcn_mfma_f32_16x16x32_bf16(aw1, qa1, z, 0, 0, 0);
        __builtin_amdgcn_s_setprio(0);
        #pragma unroll
        for (int ti = 0; ti < 2; ++ti) {
            #pragma unroll
            for (int e = 0; e < 4; ++e) {
                int p = ti * 16 + g * 4 + e;
                float vh = (ti ? rh1[e] : rh0[e]) * LOG2E;
                float vw = (ti ? rw1[e] : rw0[e]) * LOG2E;
                int kyd = p + qi - 11;
                int kxd = p + qj - 11;
                if ((unsigned)kyd < 12u) Qe[q * 32 + kyd] = f2bf(vh);
                if ((unsigned)kxd < 12u) Qe[q * 32 + 12 + kxd] = f2bf(vw);
            }
        }
    }

    // ---- deferred V scatter (Vt region: no cross-wave hazard pre-B1) ----
    VSCAT(vV0, vb0);
    VSCAT(vV1, vb1);
    if (t < 64) VSCAT(vV2, vb2);

    __syncthreads();   // B1: Ks/Qe/Vt ready

    // ---- phase 2: augmented QK^T (swapped): acc[j][e] = log2-score[16j+4g+e][q] ----
    bf16x8 qa2 = *reinterpret_cast<const bf16x8*>(&Qe[q * 32 + g * 8]);
    f32x4 acc[9];
    __builtin_amdgcn_s_setprio(1);
    #pragma unroll
    for (int j = 0; j < 9; ++j) {
        int krow = j * 16 + r;
        int sw = (r & 7) << 3;
        bf16x8 kb0 = *reinterpret_cast<const bf16x8*>(&Ks[krow * 64 + ((g * 8) ^ sw)]);
        bf16x8 kb1 = *reinterpret_cast<const bf16x8*>(&Ks[krow * 64 + ((32 + g * 8) ^ sw)]);
        f32x4 z = (f32x4){0.f, 0.f, 0.f, 0.f};
        acc[j] = __builtin_amdgcn_mfma_f32_16x16x32_bf16(kb1, qa2,
                 __builtin_amdgcn_mfma_f32_16x16x32_bf16(kb0, qa1, z, 0, 0, 0), 0, 0, 0);
    }
    __builtin_amdgcn_s_setprio(0);

    // ---- softmax (log2 domain, with max) ----
    float mx = max3f(acc[0][0], acc[0][1], acc[0][2]);
    mx = fmaxf(mx, acc[0][3]);
    #pragma unroll
    for (int j = 1; j < 9; ++j)
        mx = max3f(mx, max3f(acc[j][0], acc[j][1], acc[j][2]), acc[j][3]);
    mx = fmaxf(mx, __shfl_xor(mx, 16));
    mx = fmaxf(mx, __shfl_xor(mx, 32));
    float s0 = 0.f, s1 = 0.f, s2 = 0.f, s3 = 0.f;
    u32 pkA[9], pkB[9];
    #pragma unroll
    for (int j = 0; j < 9; ++j) {
        float e0 = exp2a(acc[j][0] - mx);
        float e1 = exp2a(acc[j][1] - mx);
        float e2 = exp2a(acc[j][2] - mx);
        float e3 = exp2a(acc[j][3] - mx);
        s0 += e0; s1 += e1; s2 += e2; s3 += e3;
        pkA[j] = cvtpk(e0, e1);
        pkB[j] = cvtpk(e2, e3);
    }
    float sum = (s0 + s1) + (s2 + s3);
    sum += __shfl_xor(sum, 16);
    sum += __shfl_xor(sum, 32);
    const float inv = __builtin_amdgcn_rcpf(sum);

    __syncthreads();   // B2: all QK reads of Ks/Qe done -> PT overlays

    // ---- write P^T[q][k] (uint2) + wave-local zero pad; PT rows are wave-local ----
    {
        const int ptb = q * PT_S;
        #pragma unroll
        for (int j = 0; j < 9; ++j)
            *reinterpret_cast<uint2*>(&PT[ptb + 16 * j + 4 * g]) = make_uint2(pkA[j], pkB[j]);
        if (g == 0) {
            *reinterpret_cast<uint4*>(&PT[ptb + 144]) = make_uint4(0u, 0u, 0u, 0u);
            *reinterpret_cast<uint4*>(&PT[ptb + 152]) = make_uint4(0u, 0u, 0u, 0u);
        }
    }

    // ---- PV (reads own wave's PT rows + Vt) ----
    const int sw0 = (r >> 3) << 3;
    const int sw1 = (2 + (r >> 3)) << 3;
    f32x4 o0 = (f32x4){0.f, 0.f, 0.f, 0.f};
    f32x4 o1 = (f32x4){0.f, 0.f, 0.f, 0.f};
    __builtin_amdgcn_s_setprio(1);
    #pragma unroll
    for (int kk = 0; kk < 5; ++kk) {
        bf16x8 pb = *reinterpret_cast<const bf16x8*>(&PT[q * PT_S + kk * 32 + g * 8]);
        bf16x8 va0 = *reinterpret_cast<const bf16x8*>(&Vt[r * VT_S + ((kk * 32 + g * 8) ^ sw0)]);
        bf16x8 va1 = *reinterpret_cast<const bf16x8*>(&Vt[(16 + r) * VT_S + ((kk * 32 + g * 8) ^ sw1)]);
        o0 = __builtin_amdgcn_mfma_f32_16x16x32_bf16(va0, pb, o0, 0, 0, 0);
        o1 = __builtin_amdgcn_mfma_f32_16x16x32_bf16(va1, pb, o1, 0, 0, 0);
    }
    __builtin_amdgcn_s_setprio(0);
    {
        uint2 st0, st1;
        st0.x = cvtpk(o0[0] * inv, o0[1] * inv);
        st0.y = cvtpk(o0[2] * inv, o0[3] * inv);
        st1.x = cvtpk(o1[0] * inv, o1[1] * inv);
        st1.y = cvtpk(o1[2] * inv, o1[3] * inv);
        *reinterpret_cast<uint2*>(Ob + qrow * 256 + n * 32 + g * 4) = st0;
        *reinterpret_cast<uint2*>(Ob + qrow * 256 + n * 32 + 16 + g * 4) = st1;
    }
}

extern "C" void kernel_launch(void* const* d_in, const int* in_sizes, int n_in,
                              void* d_out, int out_size, void* d_ws, size_t ws_size,
                              hipStream_t stream) {
    const float* x     = (const float*)d_in[0];
    const float* w_q   = (const float*)d_in[1];
    const float* w_kv  = (const float*)d_in[2];
    const float* w_out = (const float*)d_in[3];
    const float* emb_h = (const float*)d_in[4];
    const float* emb_w = (const float*)d_in[5];

    u16* xb = (u16*)d_out;                               // 32MB, dead after gemm_qkv6
    u16* Qb = (u16*)((char*)d_out + (size_t)33554432);   // 32MB, dead after attn
    char* ws = (char*)d_ws;
    u16* KVb   = (u16*)(ws);                             // 64MB
    u16* Ob    = (u16*)(ws + (size_t)67108864);          // 32MB
    u16* wT    = (u16*)(ws + (size_t)100663296);         // [768][256] bf16 = 384KB
    u16* woutT = (u16*)(ws + (size_t)100663296 + 393216);// 128KB
    u16* embT  = (u16*)(ws + (size_t)100663296 + 524288);// 2048 u16 = 4KB

    dim3 blk(256);
    conv_prep<<<dim3(9218), blk, 0, stream>>>(x, xb, w_q, w_kv, w_out, wT, woutT,
                                              emb_h, emb_w, embT);
    gemm_qkv6<<<dim3(3072), blk, 0, stream>>>(xb, wT, Qb, KVb);
    attn_mfma<<<dim3(8192), blk, 0, stream>>>(Qb, KVb, embT, Ob);
    mfma_gemm<<<dim3(1024), blk, 0, stream>>>(Ob, woutT, (float*)d_out, 256);
}

// Round 21
// 131.641 us; speedup vs baseline: 1.0417x; 1.0417x over previous
//
#include <hip/hip_runtime.h>
#include <hip/hip_bf16.h>
#include <cstdint>

// HaloAttention: B=4, H=W=128, C=256, 8 heads, kd=32, block=8, halo=2, kvk=12.
// conv_prep -> gemm_qkv6 (BK=64, XCD-swizzled col tiles) -> attn (augmented-K,
// log2 softmax, T14 async staging, setprio, 2 barriers) -> mfma_gemm (f32, XCD).
// R19 configuration: session best (131.8 us).

#define KVK 12
#define NKEYS 144
#define VT_S 160
#define PT_S 168
#define LOG2E 1.4426950408889634f

typedef unsigned int u32;
typedef unsigned long long u64;
typedef unsigned short u16;
typedef __attribute__((ext_vector_type(8))) __bf16 bf16x8;
typedef __attribute__((ext_vector_type(4))) float f32x4;

__device__ __forceinline__ u16 f2bf(float f) {
    u32 x = __float_as_uint(f);
    return (u16)((x + 0x7fffu + ((x >> 16) & 1u)) >> 16);
}
__device__ __forceinline__ u32 cvtpk(float lo, float hi) {
    u32 d;
    asm("v_cvt_pk_bf16_f32 %0, %1, %2" : "=v"(d) : "v"(lo), "v"(hi));
    return d;
}
__device__ __forceinline__ float max3f(float a, float b, float c) {
    float d;
    asm("v_max3_f32 %0, %1, %2, %3" : "=v"(d) : "v"(a), "v"(b), "v"(c));
    return d;
}
__device__ __forceinline__ float exp2a(float x) {
    float d;
    asm("v_exp_f32 %0, %1" : "=v"(d) : "v"(x));
    return d;
}
__device__ __forceinline__ void gload16(const void* g, void* l) {
    __builtin_amdgcn_global_load_lds(
        (const __attribute__((address_space(1))) void*)g,
        (__attribute__((address_space(3))) void*)l, 16, 0, 0);
}
__device__ __forceinline__ u32 pack2(float lo, float hi) {
    return (u32)f2bf(lo) | ((u32)f2bf(hi) << 16);
}

// ---------------- conv (x->bf16) + weight/emb prep, one dispatch ----------------
__global__ __launch_bounds__(256) void conv_prep(const float* __restrict__ x,
                                                 u16* __restrict__ xb,
                                                 const float* __restrict__ wq,
                                                 const float* __restrict__ wkv,
                                                 const float* __restrict__ wout,
                                                 u16* __restrict__ wT,
                                                 u16* __restrict__ woutT,
                                                 const float* __restrict__ emb_h,
                                                 const float* __restrict__ emb_w,
                                                 u16* __restrict__ embT) {
    int blk = blockIdx.x, t = threadIdx.x;
    if (blk < 8192) {
        int i = blk * 256 + t;
        const float4* p = reinterpret_cast<const float4*>(x) + (long)i * 2;
        float4 a = p[0], b = p[1];
        uint4 o;
        o.x = pack2(a.x, a.y); o.y = pack2(a.z, a.w);
        o.z = pack2(b.x, b.y); o.w = pack2(b.z, b.w);
        reinterpret_cast<uint4*>(xb)[i] = o;
        return;
    }
    blk -= 8192;
    if (blk < 256) {
        int idx = blk * 256 + t; int nn = idx >> 8, k = idx & 255;
        wT[idx] = f2bf(wq[(long)k * 256 + nn]);
    } else if (blk < 768) {
        int idx = (blk - 256) * 256 + t; int nn = idx >> 8, k = idx & 255;
        float v = wkv[(long)k * 512 + nn];
        if ((nn & 32) == 0) v *= 0.2550348642f;  // (1/sqrt(32)) * log2(e)
        wT[65536 + idx] = f2bf(v);
    } else if (blk < 1024) {
        int idx = (blk - 768) * 256 + t; int nn = idx >> 8, k = idx & 255;
        woutT[idx] = f2bf(wout[(long)k * 256 + nn]);
    } else if (blk == 1024) {
        for (int i = t; i < 1024; i += 256) {
            int p = i >> 5, d = i & 31;
            embT[i] = (p < 23) ? f2bf(emb_h[d * 23 + p]) : 0;
        }
    } else {
        for (int i = t; i < 1024; i += 256) {
            int p = i >> 5, d = i & 31;
            embT[1024 + i] = (p < 23) ? f2bf(emb_w[d * 23 + p]) : 0;
        }
    }
}

// -------- QKV GEMM: [Q|KV] = xb @ [wq|wkv]^T, BK=64, XCD-swizzled 1D grid --------
__global__ __launch_bounds__(256) void gemm_qkv6(const u16* __restrict__ A,
                                                 const u16* __restrict__ WT,
                                                 u16* __restrict__ Qb,
                                                 u16* __restrict__ KVb) {
    __shared__ u16 As[8192];   // [2 panels][128 rows][32 k]
    __shared__ u16 Bs[8192];
    const int t = threadIdx.x;
    const int bid = blockIdx.x;
    const int mIdx = (bid / 48) * 8 + (bid & 7);
    const int nt = (bid >> 3) % 6;
    const int w = t >> 6, lane = t & 63;
    const long m0 = (long)mIdx * 128;
    const long n0 = (long)nt * 128;
    const int wr = w >> 1, wc = w & 1;
    const int r = lane & 15, g = lane >> 4;

    f32x4 acc[4][4];
    #pragma unroll
    for (int i = 0; i < 4; ++i)
        #pragma unroll
        for (int j = 0; j < 4; ++j) acc[i][j] = (f32x4){0.f, 0.f, 0.f, 0.f};

    const u16* Ags[4];
    const u16* Bgs[4];
    #pragma unroll
    for (int cq = 0; cq < 4; ++cq) {
        int u = cq * 256 + w * 64 + lane;
        int panel = u >> 9, row = (u >> 2) & 127, col8 = (u & 3) * 8;
        Ags[cq] = A + (m0 + row) * 256 + panel * 32 + col8;
        Bgs[cq] = WT + (n0 + row) * 256 + panel * 32 + col8;
    }

    for (int k0 = 0; k0 < 256; k0 += 64) {
        #pragma unroll
        for (int cq = 0; cq < 4; ++cq) {
            gload16(Ags[cq] + k0, &As[cq * 2048 + w * 512]);
            gload16(Bgs[cq] + k0, &Bs[cq * 2048 + w * 512]);
        }
        __syncthreads();
        #pragma unroll
        for (int kk = 0; kk < 2; ++kk) {
            bf16x8 a[4], b[4];
            #pragma unroll
            for (int i = 0; i < 4; ++i)
                a[i] = *reinterpret_cast<const bf16x8*>(
                    &As[kk * 4096 + (wr * 64 + i * 16 + r) * 32 + g * 8]);
            #pragma unroll
            for (int j = 0; j < 4; ++j)
                b[j] = *reinterpret_cast<const bf16x8*>(
                    &Bs[kk * 4096 + (wc * 64 + j * 16 + r) * 32 + g * 8]);
            #pragma unroll
            for (int i = 0; i < 4; ++i)
                #pragma unroll
                for (int j = 0; j < 4; ++j)
                    acc[i][j] = __builtin_amdgcn_mfma_f32_16x16x32_bf16(b[j], a[i], acc[i][j], 0, 0, 0);
        }
        __syncthreads();
    }

    const bool isQ = (nt < 2);
    #pragma unroll
    for (int i = 0; i < 4; ++i) {
        long row = m0 + wr * 64 + i * 16 + r;
        #pragma unroll
        for (int j = 0; j < 4; ++j) {
            long colb = n0 + wc * 64 + j * 16 + g * 4;
            uint2 st;
            st.x = cvtpk(acc[i][j][0], acc[i][j][1]);
            st.y = cvtpk(acc[i][j][2], acc[i][j][3]);
            if (isQ) *reinterpret_cast<uint2*>(Qb + row * 256 + colb) = st;
            else     *reinterpret_cast<uint2*>(KVb + row * 512 + colb - 256) = st;
        }
    }
}

// ------- MFMA GEMM (final): C f32 = A bf16 * BT^T, BK=64, XCD-swizzled 1D grid ---
__global__ __launch_bounds__(256) void mfma_gemm(const u16* __restrict__ A,
                                                 const u16* __restrict__ BT,
                                                 float* __restrict__ C, int N) {
    __shared__ u16 As[8192];
    __shared__ u16 Bs[8192];
    const int t = threadIdx.x;
    const int bid = blockIdx.x;
    const int mIdx = (bid / 16) * 8 + (bid & 7);
    const int nt = (bid >> 3) & 1;
    const int w = t >> 6, lane = t & 63;
    const long m0 = (long)mIdx * 128;
    const long n0 = (long)nt * 128;
    const int wr = w >> 1, wc = w & 1;
    const int r = lane & 15, g = lane >> 4;

    f32x4 acc[4][4];
    #pragma unroll
    for (int i = 0; i < 4; ++i)
        #pragma unroll
        for (int j = 0; j < 4; ++j) acc[i][j] = (f32x4){0.f, 0.f, 0.f, 0.f};

    const u16* Ags[4];
    const u16* Bgs[4];
    #pragma unroll
    for (int cq = 0; cq < 4; ++cq) {
        int u = cq * 256 + w * 64 + lane;
        int panel = u >> 9, row = (u >> 2) & 127, col8 = (u & 3) * 8;
        Ags[cq] = A + (m0 + row) * 256 + panel * 32 + col8;
        Bgs[cq] = BT + (n0 + row) * 256 + panel * 32 + col8;
    }

    for (int k0 = 0; k0 < 256; k0 += 64) {
        #pragma unroll
        for (int cq = 0; cq < 4; ++cq) {
            gload16(Ags[cq] + k0, &As[cq * 2048 + w * 512]);
            gload16(Bgs[cq] + k0, &Bs[cq * 2048 + w * 512]);
        }
        __syncthreads();
        #pragma unroll
        for (int kk = 0; kk < 2; ++kk) {
            bf16x8 a[4], b[4];
            #pragma unroll
            for (int i = 0; i < 4; ++i)
                a[i] = *reinterpret_cast<const bf16x8*>(
                    &As[kk * 4096 + (wr * 64 + i * 16 + r) * 32 + g * 8]);
            #pragma unroll
            for (int j = 0; j < 4; ++j)
                b[j] = *reinterpret_cast<const bf16x8*>(
                    &Bs[kk * 4096 + (wc * 64 + j * 16 + r) * 32 + g * 8]);
            #pragma unroll
            for (int i = 0; i < 4; ++i)
                #pragma unroll
                for (int j = 0; j < 4; ++j)
                    acc[i][j] = __builtin_amdgcn_mfma_f32_16x16x32_bf16(b[j], a[i], acc[i][j], 0, 0, 0);
        }
        __syncthreads();
    }

    #pragma unroll
    for (int i = 0; i < 4; ++i) {
        long row = m0 + wr * 64 + i * 16 + r;
        #pragma unroll
        for (int j = 0; j < 4; ++j) {
            long colb = n0 + wc * 64 + j * 16 + g * 4;
            float4 st = make_float4(acc[i][j][0], acc[i][j][1], acc[i][j][2], acc[i][j][3]);
            *reinterpret_cast<float4*>(C + row * N + colb) = st;
        }
    }
}

// ---------------- MFMA Attention: T14 async staging + setprio, 2 barriers --------
// Pre-barrier order: issue loads -> load-independent work (one-hot build, pads)
// -> K LDS writes (first load use) -> phase1 rel-MFMA -> deferred V scatter -> B1.
#define UNITLOAD(U, VK, VV, KD, VB) {                                          \
    int kk_ = (U) >> 2, p_ = (U) & 3;                                          \
    int ky_ = (kk_ * 171) >> 11, kx_ = kk_ - 12 * ky_;                         \
    int gy_ = by * 8 + ky_ - 2, gx_ = bx * 8 + kx_ - 2;                        \
    if (((unsigned)gy_ < 128u) && ((unsigned)gx_ < 128u)) {                    \
        const u16* bp_ = KVb + (((long)b * 128 + gy_) * 128 + gx_) * 512 + n * 64 + p_ * 8; \
        VK = *reinterpret_cast<const uint4*>(bp_);                             \
        VV = *reinterpret_cast<const uint4*>(bp_ + 32);                        \
    }                                                                          \
    KD = kk_ * 64 + ((p_ * 8) ^ ((kk_ & 7) << 3));                             \
    VB = (p_ * 8) * VT_S + (kk_ ^ (p_ << 3));                                  \
}
#define VSCAT(VV, VB) {                                                        \
    u16 tmp_[8];                                                               \
    *reinterpret_cast<uint4*>(tmp_) = VV;                                      \
    _Pragma("unroll")                                                          \
    for (int i_ = 0; i_ < 8; ++i_) Vt[(VB) + i_ * VT_S] = tmp_[i_];            \
}

__global__ __launch_bounds__(256, 5) void attn_mfma(const u16* __restrict__ Qb,
                                                    const u16* __restrict__ KVb,
                                                    const u16* __restrict__ embT,
                                                    u16* __restrict__ Ob) {
    __shared__ __align__(16) char blob[22528];
    u16* Ks  = (u16*)blob;               // [144][64] swizzled: 0..31 K*s*l2e, 32..55 onehots
    u16* Qe  = (u16*)(blob + 18432);     // [64][32]: rel*log2e dims + zero tail
    u16* PT  = (u16*)blob;               // [64][PT_S] overlay after QK (21504B)
    __shared__ u16 Vt[32 * VT_S];        // V^T [d][k], swizzled, cols 144..159 zero

    const int gblk = blockIdx.x;
    const int n = gblk & 7;
    const int bx = (gblk >> 3) & 15;
    const int by = (gblk >> 7) & 15;
    const int b = gblk >> 11;
    const int t = threadIdx.x;
    const int w = t >> 6, lane = t & 63;
    const int g = lane >> 4, r = lane & 15;

    const int q = w * 16 + r;
    const int qi = q >> 3, qj = q & 7;
    const long qrow = ((long)b * 128 + by * 8 + qi) * 128 + bx * 8 + qj;

    // ---- issue ALL global loads up front ----
    bf16x8 qa1 = *reinterpret_cast<const bf16x8*>(Qb + qrow * 256 + n * 32 + g * 8);
    bf16x8 ah0 = *reinterpret_cast<const bf16x8*>(embT + r * 32 + g * 8);
    bf16x8 ah1 = *reinterpret_cast<const bf16x8*>(embT + (16 + r) * 32 + g * 8);
    bf16x8 aw0 = *reinterpret_cast<const bf16x8*>(embT + 1024 + r * 32 + g * 8);
    bf16x8 aw1 = *reinterpret_cast<const bf16x8*>(embT + 1024 + (16 + r) * 32 + g * 8);

    uint4 z4 = make_uint4(0u, 0u, 0u, 0u);
    uint4 vK0 = z4, vV0 = z4, vK1 = z4, vV1 = z4, vK2 = z4, vV2 = z4;
    int kd0 = 0, vb0 = 0, kd1 = 0, vb1 = 0, kd2 = 0, vb2 = 0;
    UNITLOAD(t, vK0, vV0, kd0, vb0);
    UNITLOAD(t + 256, vK1, vV1, kd1, vb1);
    if (t < 64) UNITLOAD(t + 512, vK2, vV2, kd2, vb2);

    // ---- load-independent work first: one-hot ext cols + pads (covers latency) ----
    for (int u = t; u < 576; u += 256) {
        int kk = u >> 2, uu = u & 3;
        int ky = (kk * 171) >> 11;
        int kx = kk - 12 * ky;
        int hy = ky - 8 * uu;
        int hx = 12 + kx - 8 * uu;
        u64 lo = 0, hi = 0;
        if ((unsigned)hy < 4u) lo |= 0x3F80ULL << (hy * 16);
        else if ((unsigned)hy < 8u) hi |= 0x3F80ULL << ((hy - 4) * 16);
        if ((unsigned)hx < 4u) lo |= 0x3F80ULL << (hx * 16);
        else if ((unsigned)hx < 8u) hi |= 0x3F80ULL << ((hx - 4) * 16);
        int col = (32 + uu * 8) ^ ((kk & 7) << 3);
        u64* dst = reinterpret_cast<u64*>(&Ks[kk * 64 + col]);
        dst[0] = lo;
        dst[1] = hi;
    }
    if (t < 64) *reinterpret_cast<uint4*>(&Qe[t * 32 + 24]) = z4;
    if (t >= 224) {
        int d = t - 224;
        int sw = ((d >> 3) & 3) << 3;
        *reinterpret_cast<uint4*>(&Vt[d * VT_S + (144 ^ sw)]) = z4;
        *reinterpret_cast<uint4*>(&Vt[d * VT_S + (152 ^ sw)]) = z4;
    }

    // ---- K -> LDS (first use of the KV loads) ----
    *reinterpret_cast<uint4*>(&Ks[kd0]) = vK0;
    *reinterpret_cast<uint4*>(&Ks[kd1]) = vK1;
    if (t < 64) *reinterpret_cast<uint4*>(&Ks[kd2]) = vK2;

    // ---- phase 1: rel-MFMA -> Qe (x log2e) ----
    {
        f32x4 z = (f32x4){0.f, 0.f, 0.f, 0.f};
        __builtin_amdgcn_s_setprio(1);
        f32x4 rh0 = __builtin_amdgcn_mfma_f32_16x16x32_bf16(ah0, qa1, z, 0, 0, 0);
        f32x4 rh1 = __builtin_amdgcn_mfma_f32_16x16x32_bf16(ah1, qa1, z, 0, 0, 0);
        f32x4 rw0 = __builtin_amdgcn_mfma_f32_16x16x32_bf16(aw0, qa1, z, 0, 0, 0);
        f32x4 rw1 = __builtin_amdgcn_mfma_f32_16x16x32_bf16(aw1, qa1, z, 0, 0, 0);
        __builtin_amdgcn_s_setprio(0);
        #pragma unroll
        for (int ti = 0; ti < 2; ++ti) {
            #pragma unroll
            for (int e = 0; e < 4; ++e) {
                int p = ti * 16 + g * 4 + e;
                float vh = (ti ? rh1[e] : rh0[e]) * LOG2E;
                float vw = (ti ? rw1[e] : rw0[e]) * LOG2E;
                int kyd = p + qi - 11;
                int kxd = p + qj - 11;
                if ((unsigned)kyd < 12u) Qe[q * 32 + kyd] = f2bf(vh);
                if ((unsigned)kxd < 12u) Qe[q * 32 + 12 + kxd] = f2bf(vw);
            }
        }
    }

    // ---- deferred V scatter (Vt region: no cross-wave hazard pre-B1) ----
    VSCAT(vV0, vb0);
    VSCAT(vV1, vb1);
    if (t < 64) VSCAT(vV2, vb2);

    __syncthreads();   // B1: Ks/Qe/Vt ready

    // ---- phase 2: augmented QK^T (swapped): acc[j][e] = log2-score[16j+4g+e][q] ----
    bf16x8 qa2 = *reinterpret_cast<const bf16x8*>(&Qe[q * 32 + g * 8]);
    f32x4 acc[9];
    __builtin_amdgcn_s_setprio(1);
    #pragma unroll
    for (int j = 0; j < 9; ++j) {
        int krow = j * 16 + r;
        int sw = (r & 7) << 3;
        bf16x8 kb0 = *reinterpret_cast<const bf16x8*>(&Ks[krow * 64 + ((g * 8) ^ sw)]);
        bf16x8 kb1 = *reinterpret_cast<const bf16x8*>(&Ks[krow * 64 + ((32 + g * 8) ^ sw)]);
        f32x4 z = (f32x4){0.f, 0.f, 0.f, 0.f};
        acc[j] = __builtin_amdgcn_mfma_f32_16x16x32_bf16(kb1, qa2,
                 __builtin_amdgcn_mfma_f32_16x16x32_bf16(kb0, qa1, z, 0, 0, 0), 0, 0, 0);
    }
    __builtin_amdgcn_s_setprio(0);

    // ---- softmax (log2 domain, with max) ----
    float mx = max3f(acc[0][0], acc[0][1], acc[0][2]);
    mx = fmaxf(mx, acc[0][3]);
    #pragma unroll
    for (int j = 1; j < 9; ++j)
        mx = max3f(mx, max3f(acc[j][0], acc[j][1], acc[j][2]), acc[j][3]);
    mx = fmaxf(mx, __shfl_xor(mx, 16));
    mx = fmaxf(mx, __shfl_xor(mx, 32));
    float s0 = 0.f, s1 = 0.f, s2 = 0.f, s3 = 0.f;
    u32 pkA[9], pkB[9];
    #pragma unroll
    for (int j = 0; j < 9; ++j) {
        float e0 = exp2a(acc[j][0] - mx);
        float e1 = exp2a(acc[j][1] - mx);
        float e2 = exp2a(acc[j][2] - mx);
        float e3 = exp2a(acc[j][3] - mx);
        s0 += e0; s1 += e1; s2 += e2; s3 += e3;
        pkA[j] = cvtpk(e0, e1);
        pkB[j] = cvtpk(e2, e3);
    }
    float sum = (s0 + s1) + (s2 + s3);
    sum += __shfl_xor(sum, 16);
    sum += __shfl_xor(sum, 32);
    const float inv = __builtin_amdgcn_rcpf(sum);

    __syncthreads();   // B2: all QK reads of Ks/Qe done -> PT overlays

    // ---- write P^T[q][k] (uint2) + wave-local zero pad; PT rows are wave-local ----
    {
        const int ptb = q * PT_S;
        #pragma unroll
        for (int j = 0; j < 9; ++j)
            *reinterpret_cast<uint2*>(&PT[ptb + 16 * j + 4 * g]) = make_uint2(pkA[j], pkB[j]);
        if (g == 0) {
            *reinterpret_cast<uint4*>(&PT[ptb + 144]) = make_uint4(0u, 0u, 0u, 0u);
            *reinterpret_cast<uint4*>(&PT[ptb + 152]) = make_uint4(0u, 0u, 0u, 0u);
        }
    }

    // ---- PV (reads own wave's PT rows + Vt) ----
    const int sw0 = (r >> 3) << 3;
    const int sw1 = (2 + (r >> 3)) << 3;
    f32x4 o0 = (f32x4){0.f, 0.f, 0.f, 0.f};
    f32x4 o1 = (f32x4){0.f, 0.f, 0.f, 0.f};
    __builtin_amdgcn_s_setprio(1);
    #pragma unroll
    for (int kk = 0; kk < 5; ++kk) {
        bf16x8 pb = *reinterpret_cast<const bf16x8*>(&PT[q * PT_S + kk * 32 + g * 8]);
        bf16x8 va0 = *reinterpret_cast<const bf16x8*>(&Vt[r * VT_S + ((kk * 32 + g * 8) ^ sw0)]);
        bf16x8 va1 = *reinterpret_cast<const bf16x8*>(&Vt[(16 + r) * VT_S + ((kk * 32 + g * 8) ^ sw1)]);
        o0 = __builtin_amdgcn_mfma_f32_16x16x32_bf16(va0, pb, o0, 0, 0, 0);
        o1 = __builtin_amdgcn_mfma_f32_16x16x32_bf16(va1, pb, o1, 0, 0, 0);
    }
    __builtin_amdgcn_s_setprio(0);
    {
        uint2 st0, st1;
        st0.x = cvtpk(o0[0] * inv, o0[1] * inv);
        st0.y = cvtpk(o0[2] * inv, o0[3] * inv);
        st1.x = cvtpk(o1[0] * inv, o1[1] * inv);
        st1.y = cvtpk(o1[2] * inv, o1[3] * inv);
        *reinterpret_cast<uint2*>(Ob + qrow * 256 + n * 32 + g * 4) = st0;
        *reinterpret_cast<uint2*>(Ob + qrow * 256 + n * 32 + 16 + g * 4) = st1;
    }
}

extern "C" void kernel_launch(void* const* d_in, const int* in_sizes, int n_in,
                              void* d_out, int out_size, void* d_ws, size_t ws_size,
                              hipStream_t stream) {
    const float* x     = (const float*)d_in[0];
    const float* w_q   = (const float*)d_in[1];
    const float* w_kv  = (const float*)d_in[2];
    const float* w_out = (const float*)d_in[3];
    const float* emb_h = (const float*)d_in[4];
    const float* emb_w = (const float*)d_in[5];

    u16* xb = (u16*)d_out;                               // 32MB, dead after gemm_qkv6
    u16* Qb = (u16*)((char*)d_out + (size_t)33554432);   // 32MB, dead after attn
    char* ws = (char*)d_ws;
    u16* KVb   = (u16*)(ws);                             // 64MB
    u16* Ob    = (u16*)(ws + (size_t)67108864);          // 32MB
    u16* wT    = (u16*)(ws + (size_t)100663296);         // [768][256] bf16 = 384KB
    u16* woutT = (u16*)(ws + (size_t)100663296 + 393216);// 128KB
    u16* embT  = (u16*)(ws + (size_t)100663296 + 524288);// 2048 u16 = 4KB

    dim3 blk(256);
    conv_prep<<<dim3(9218), blk, 0, stream>>>(x, xb, w_q, w_kv, w_out, wT, woutT,
                                              emb_h, emb_w, embT);
    gemm_qkv6<<<dim3(3072), blk, 0, stream>>>(xb, wT, Qb, KVb);
    attn_mfma<<<dim3(8192), blk, 0, stream>>>(Qb, KVb, embT, Ob);
    mfma_gemm<<<dim3(1024), blk, 0, stream>>>(Ob, woutT, (float*)d_out, 256);
}